// Round 2
// baseline (2109.299 us; speedup 1.0000x reference)
//
#include <hip/hip_runtime.h>
#include <stdint.h>

// GRU forward: V=32000 E=128 H=256 B=8 S=512.
// Reference dtypes are float32; a detector kernel resolves f32-vs-bf16 storage
// at runtime and exactly one templated variant of each kernel does the work.
// ws: gi f32 [512][8][768] (12.58MB) | hidden fp16 [4096][256] (2.1MB) | flag
//
// k_scan v3: one CU per batch (8 blocks x 1024 thr). MFMA floor is 384
// inst/step/CU (~1862 cyc); v3 strips the ~1500 cyc/step of overhead:
//  - raw s_barrier + lgkmcnt(0) only (no vmcnt(0) drain per step)
//  - h state lives in a 32-slot LDS ring that doubles as the A-operand and
//    the hidden-store staging; flushed every 16 steps, fire-and-forget
//  - gi prefetched into registers one step ahead (no gi LDS buffer)
//  - b_hh folded into MFMA acc init; A-reads unmasked uniform broadcast

typedef __attribute__((ext_vector_type(8))) _Float16 half8;   // 4 VGPRs
typedef __attribute__((ext_vector_type(4))) _Float16 half4;   // 2 VGPRs
typedef __attribute__((ext_vector_type(4))) float float4v;
typedef __attribute__((ext_vector_type(4))) float facc4;      // MFMA acc
typedef __attribute__((ext_vector_type(4))) unsigned short ushort4v;

#define GI_BYTES   (512 * 8 * 768 * 4)        // 12582912
#define HID_BYTES  (4096 * 256 * 2)           // 2097152
#define FLAG_OFF   (GI_BYTES + HID_BYTES)

__device__ __forceinline__ float b2f(unsigned short u) {
  union { unsigned int i; float f; } v; v.i = ((unsigned int)u) << 16; return v.f;
}
__device__ __forceinline__ unsigned short f2b(float f) {
  union { float f; unsigned int i; } v; v.f = f;
  unsigned int r = v.i + 0x7FFFu + ((v.i >> 16) & 1u);  // RNE
  return (unsigned short)(r >> 16);
}
template<bool BF> __device__ __forceinline__ float ldf(const void* p, int i) {
  if constexpr (BF) return b2f(((const unsigned short*)p)[i]);
  else              return ((const float*)p)[i];
}
template<bool BF> __device__ __forceinline__ float4v ld4(const void* p, int i) {
  float4v r;
  if constexpr (BF) {
    ushort4v u = *reinterpret_cast<const ushort4v*>((const unsigned short*)p + i);
#pragma unroll
    for (int j = 0; j < 4; ++j) r[j] = b2f(u[j]);
  } else {
    r = *reinterpret_cast<const float4v*>((const float*)p + i);
  }
  return r;
}

// raw workgroup barrier: waits LDS ops only; leaves global loads/stores in
// flight across the barrier (the compiler's __syncthreads would vmcnt(0)).
// sched_barrier(0) fences per guide rule #18.
__device__ __forceinline__ void bar_lgkm() {
  __builtin_amdgcn_sched_barrier(0);
  asm volatile("s_waitcnt lgkmcnt(0)" ::: "memory");
  __builtin_amdgcn_sched_barrier(0);
  __builtin_amdgcn_s_barrier();
  __builtin_amdgcn_sched_barrier(0);
}

// ---- dtype detector: bf16 storage => low u16 of each u32 word has a small-
// value bf16 exponent pattern; f32 storage => those bits are uniform mantissa.
__global__ void k_detect(const unsigned int* __restrict__ emb_raw,
                         int* __restrict__ flag) {
  int tid = threadIdx.x;
  unsigned int u = emb_raw[tid];
  unsigned int lo = u & 0xFFFFu;
  unsigned int ex = (lo >> 7) & 0xFFu;        // bf16 exponent field
  int hit = ((ex >= 96u && ex <= 127u) || lo == 0u) ? 1 : 0;
  unsigned long long m = __ballot(hit);
  if (tid == 0) flag[0] = (__popcll(m) >= 40) ? 1 : 0;
}

// ---- kernel 1: gi[s][b][g] = emb[t[b,s]] . w_ih[g,:] + b_ih[g]  (f32 out) ----
template<bool BF>
__global__ __launch_bounds__(256, 4) void k_gi(
    const int* __restrict__ flag, const int* __restrict__ t,
    const void* __restrict__ emb, const void* __restrict__ w_ih,
    const void* __restrict__ b_ih, float* __restrict__ gi)
{
  if (*flag != (BF ? 1 : 0)) return;
  alignas(16) __shared__ float x_lds[4][128];
  const int n0 = blockIdx.x * 4;               // 4 tokens per block
  const int tid = threadIdx.x;
  for (int i = tid; i < 512; i += 256) {
    int tk = i >> 7, e = i & 127;
    int n = n0 + tk, s = n >> 3, b = n & 7;
    int tok = t[b * 512 + s];
    x_lds[tk][e] = ldf<BF>(emb, tok * 128 + e);
  }
  __syncthreads();
#pragma unroll
  for (int gg = 0; gg < 3; ++gg) {
    int g = gg * 256 + tid;
    float bias = ldf<BF>(b_ih, g);
    float a0 = bias, a1 = bias, a2 = bias, a3 = bias;
    for (int kb = 0; kb < 32; ++kb) {
      float4v w4 = ld4<BF>(w_ih, g * 128 + kb * 4);
#pragma unroll
      for (int j = 0; j < 4; ++j) {
        float w = w4[j]; int k = kb * 4 + j;
        a0 = fmaf(w, x_lds[0][k], a0);
        a1 = fmaf(w, x_lds[1][k], a1);
        a2 = fmaf(w, x_lds[2][k], a2);
        a3 = fmaf(w, x_lds[3][k], a3);
      }
    }
    gi[(n0 + 0) * 768 + g] = a0;
    gi[(n0 + 1) * 768 + g] = a1;
    gi[(n0 + 2) * 768 + g] = a2;
    gi[(n0 + 3) * 768 + g] = a3;
  }
}

// ---- kernel 2: serial GRU scan, one block per batch, 16 waves ----
template<bool BF>
__global__ __launch_bounds__(1024) void k_scan(
    const int* __restrict__ flag, const void* __restrict__ w_hh,
    const void* __restrict__ b_hh, const void* __restrict__ h0,
    const float* __restrict__ gi, _Float16* __restrict__ hidden)
{
  if (*flag != (BF ? 1 : 0)) return;
  // 32-slot h ring: slot s&31 = h produced at step s (= A operand of step
  // s+1, and the staging row for hidden[s]). Reuse distance 32 steps; flush
  // every 16 -> 17-barrier separation, race-free.
  alignas(16) __shared__ _Float16 hs[32][256];   // 16KB

  const int tid = threadIdx.x;
  const int b = blockIdx.x;                      // batch index
  const int wave = tid >> 6, lane = tid & 63;
  const int l15 = lane & 15, q = lane >> 4;
  const int qo = q * 8;                          // k sub-offset within kt
  const int j = (wave << 4) + l15;               // this lane's gate column

  // B fragments: tile tt = gate (r,z,n), cols j in [wave*16, wave*16+16).
  // B[k][col] = w_hh[row][k]; lane: col=l15 -> row = tt*256 + j,
  // k = kt*32 + q*8 + jj. Same mapping as the verified v2 kernel.
  half8 bfr[3][8];
#pragma unroll
  for (int tt = 0; tt < 3; ++tt) {
    int nrow = tt * 256 + j;
#pragma unroll
    for (int kt = 0; kt < 8; ++kt) {
      int base = nrow * 256 + kt * 32 + qo;
      float4v x0 = ld4<BF>(w_hh, base), x1 = ld4<BF>(w_hh, base + 4);
      half8 h;
#pragma unroll
      for (int jj = 0; jj < 4; ++jj) { h[jj] = (_Float16)x0[jj]; h[4 + jj] = (_Float16)x1[jj]; }
      bfr[tt][kt] = h;
    }
  }

  // per-lane biases (fold into acc init; C layout col=l15 -> same bias for
  // all 4 acc rows of a lane)
  const float bh_r = ldf<BF>(b_hh, j);
  const float bh_z = ldf<BF>(b_hh, 256 + j);
  const float bh_n = ldf<BF>(b_hh, 512 + j);

  if (tid < 256) hs[31][tid] = (_Float16)ldf<BF>(h0, tid);   // h(-1) slot
  float hreg = (lane < 16) ? ldf<BF>(h0, j) : 0.f;           // f32 across steps

  // gi(s=0) into registers (lanes<16 only: 3 scalars each)
  float gr_c = 0.f, gz_c = 0.f, gn_c = 0.f;
  if (lane < 16) {
    const float* g0 = gi + b * 768 + j;
    gr_c = g0[0]; gz_c = g0[256]; gn_c = g0[512];
  }
  __syncthreads();   // prologue sync (full drain OK once)

  _Float16* hid = hidden + b * 512 * 256;

  for (int s = 0; s < 512; ++s) {
    // prefetch gi(s+1) into regs; latency hides under the MFMA phase
    float gr_n = 0.f, gz_n = 0.f, gn_n = 0.f;
    if (lane < 16 && s < 511) {
      const float* gp = gi + (s + 1) * 6144 + b * 768 + j;
      gr_n = gp[0]; gz_n = gp[256]; gn_n = gp[512];
    }

    const _Float16* ap = &hs[(s + 31) & 31][0];   // h(s-1)
    facc4 acc0 = {bh_r, bh_r, bh_r, bh_r};
    facc4 acc1 = {bh_z, bh_z, bh_z, bh_z};
    facc4 acc2 = {bh_n, bh_n, bh_n, bh_n};
    // A-reads: uniform per q (16-lane broadcast, conflict-free). Replicated
    // A rows are harmless: only C row 0 is consumed.
    half8 a0 = *reinterpret_cast<const half8*>(ap + qo);
    half8 a1;
#pragma unroll
    for (int kt = 0; kt < 8; kt += 2) {
      a1 = *reinterpret_cast<const half8*>(ap + (kt + 1) * 32 + qo);
      acc0 = __builtin_amdgcn_mfma_f32_16x16x32_f16(a0, bfr[0][kt], acc0, 0, 0, 0);
      acc1 = __builtin_amdgcn_mfma_f32_16x16x32_f16(a0, bfr[1][kt], acc1, 0, 0, 0);
      acc2 = __builtin_amdgcn_mfma_f32_16x16x32_f16(a0, bfr[2][kt], acc2, 0, 0, 0);
      if (kt + 2 < 8) a0 = *reinterpret_cast<const half8*>(ap + (kt + 2) * 32 + qo);
      acc0 = __builtin_amdgcn_mfma_f32_16x16x32_f16(a1, bfr[0][kt + 1], acc0, 0, 0, 0);
      acc1 = __builtin_amdgcn_mfma_f32_16x16x32_f16(a1, bfr[1][kt + 1], acc1, 0, 0, 0);
      acc2 = __builtin_amdgcn_mfma_f32_16x16x32_f16(a1, bfr[2][kt + 1], acc2, 0, 0, 0);
    }

    // gate math: C row 0 = (q==0, i==0) -> lanes 0..15 hold gh+bhh for
    // (batch b, col j) in acc0[0]/acc1[0]/acc2[0].
    if (lane < 16) {
      float r = 1.f / (1.f + __expf(-(gr_c + acc0[0])));
      float z = 1.f / (1.f + __expf(-(gz_c + acc1[0])));
      float xn = gn_c + r * acc2[0];               // bhh_n inside r* (ref)
      float e2 = __expf(2.f * xn);
      float nn = 1.f - 2.f / (e2 + 1.f);           // tanh
      float hnew = (1.f - z) * nn + z * hreg;
      hreg = hnew;
      hs[s & 31][j] = (_Float16)hnew;              // h(s): next A + staging
    }
    gr_c = gr_n; gz_c = gz_n; gn_c = gn_n;

    bar_lgkm();   // LDS-only wait; gi loads & hidden stores stay in flight

    if ((s & 15) == 15) {
      // flush steps s-15..s to hidden, coalesced 8B/lane, fire-and-forget
      int s0 = s - 15;
      int row = tid >> 6;                 // 0..15
      int c4 = (lane & 63) * 4;
      half4 v = *reinterpret_cast<const half4*>(&hs[(s0 + row) & 31][c4]);
      *reinterpret_cast<half4*>(hid + (s0 + row) * 256 + c4) = v;
    }
  }
}

// ---- kernel 3: out[tok][v] = hidden[tok,:] . w_out[v,:] + b_out[v] ----
template<bool BF>
__global__ __launch_bounds__(256, 2) void k_out(
    const int* __restrict__ flag, const _Float16* __restrict__ hidden,
    const void* __restrict__ w_out, const void* __restrict__ b_out,
    void* __restrict__ out)
{
  if (*flag != (BF ? 1 : 0)) return;
  alignas(16) __shared__ _Float16 Asm[128 * 72];  // [m][k], +8 pad
  alignas(16) __shared__ _Float16 Bsm[128 * 72];  // [n][k], +8 pad
  // XCD-chunked swizzle (8000 % 8 == 0, bijective): each XCD gets a
  // contiguous n-range -> w_out slice lives in exactly one L2, 32x reuse.
  const int bid0 = blockIdx.x;
  const int bid = (bid0 & 7) * 1000 + (bid0 >> 3);
  const int m0 = (bid & 31) * 128;     // 32 m-blocks inner: w_out reuse
  const int n0 = (bid >> 5) * 128;     // 250 n-blocks
  const int tid = threadIdx.x;
  const int wave = tid >> 6, lane = tid & 63;
  const int l15 = lane & 15, q = lane >> 4;
  const int wm = (wave >> 1) * 64, wn = (wave & 1) * 64;

  facc4 acc[4][4] = {};
  float bo[4];
#pragma unroll
  for (int nt = 0; nt < 4; ++nt)
    bo[nt] = ldf<BF>(b_out, n0 + wn + nt * 16 + l15);

  for (int kk = 0; kk < 4; ++kk) {
    int k0 = kk * 64;
#pragma unroll
    for (int r = 0; r < 4; ++r) {
      int row = r * 32 + (tid >> 3);
      int ch = tid & 7;
      *reinterpret_cast<half8*>(&Asm[row * 72 + ch * 8]) =
          *reinterpret_cast<const half8*>(hidden + (m0 + row) * 256 + k0 + ch * 8);
      int wbase = (n0 + row) * 256 + k0 + ch * 8;
      float4v w0 = ld4<BF>(w_out, wbase), w1 = ld4<BF>(w_out, wbase + 4);
      half8 hB;
#pragma unroll
      for (int j = 0; j < 4; ++j) { hB[j] = (_Float16)w0[j]; hB[4 + j] = (_Float16)w1[j]; }
      *reinterpret_cast<half8*>(&Bsm[row * 72 + ch * 8]) = hB;
    }
    __syncthreads();
#pragma unroll
    for (int kt = 0; kt < 2; ++kt) {
      int koff = kt * 32 + q * 8;
      half8 af[4], bf[4];
#pragma unroll
      for (int mt = 0; mt < 4; ++mt)
        af[mt] = *reinterpret_cast<const half8*>(&Asm[(wm + mt * 16 + l15) * 72 + koff]);
#pragma unroll
      for (int nt = 0; nt < 4; ++nt)
        bf[nt] = *reinterpret_cast<const half8*>(&Bsm[(wn + nt * 16 + l15) * 72 + koff]);
#pragma unroll
      for (int mt = 0; mt < 4; ++mt)
#pragma unroll
        for (int nt = 0; nt < 4; ++nt)
          acc[mt][nt] = __builtin_amdgcn_mfma_f32_16x16x32_f16(
              af[mt], bf[nt], acc[mt][nt], 0, 0, 0);
    }
    __syncthreads();
  }
#pragma unroll
  for (int mt = 0; mt < 4; ++mt) {
#pragma unroll
    for (int i = 0; i < 4; ++i) {
      int row = m0 + wm + mt * 16 + q * 4 + i;
#pragma unroll
      for (int nt = 0; nt < 4; ++nt) {
        int col = n0 + wn + nt * 16 + l15;
        float val = acc[mt][nt][i] + bo[nt];
        if constexpr (BF) ((unsigned short*)out)[row * 32000 + col] = f2b(val);
        else              ((float*)out)[row * 32000 + col] = val;
      }
    }
  }
}

extern "C" void kernel_launch(void* const* d_in, const int* in_sizes, int n_in,
                              void* d_out, int out_size, void* d_ws, size_t ws_size,
                              hipStream_t stream) {
  const int* t     = (const int*)d_in[0];
  const void* emb  = d_in[1];
  const void* h0   = d_in[2];
  const void* w_ih = d_in[3];
  const void* w_hh = d_in[4];
  const void* b_ih = d_in[5];
  const void* b_hh = d_in[6];
  const void* w_out = d_in[7];
  const void* b_out = d_in[8];

  float*     gi     = (float*)d_ws;
  _Float16*  hidden = (_Float16*)((char*)d_ws + GI_BYTES);
  int*       flag   = (int*)((char*)d_ws + FLAG_OFF);

  k_detect<<<1, 64, 0, stream>>>((const unsigned int*)emb, flag);

  k_gi<false><<<1024, 256, 0, stream>>>(flag, t, emb, w_ih, b_ih, gi);
  k_gi<true> <<<1024, 256, 0, stream>>>(flag, t, emb, w_ih, b_ih, gi);

  k_scan<false><<<8, 1024, 0, stream>>>(flag, w_hh, b_hh, h0, gi, hidden);
  k_scan<true> <<<8, 1024, 0, stream>>>(flag, w_hh, b_hh, h0, gi, hidden);

  k_out<false><<<8000, 256, 0, stream>>>(flag, hidden, w_out, b_out, d_out);
  k_out<true> <<<8000, 256, 0, stream>>>(flag, hidden, w_out, b_out, d_out);
}

// Round 4
// 2098.498 us; speedup vs baseline: 1.0051x; 1.0051x over previous
//
#include <hip/hip_runtime.h>
#include <stdint.h>

// GRU forward: V=32000 E=128 H=256 B=8 S=512.
// Reference dtypes are float32; a detector kernel resolves f32-vs-bf16 storage
// at runtime and exactly one templated variant of each kernel does the work.
// ws: gi f32 [512][8][768] (12.58MB) | hidden fp16 [4096][256] (2.1MB) | flag
//
// k_scan v4 = v2 (verified 718us) + surgical critical-path cuts:
//  - step loop unrolled x8: buffer parity p=u&1 is compile-time, so the
//    compiler can hoist gi_sh[p] reads to just after the barrier and form
//    constant LDS addresses (v2's runtime p blocked both)
//  - hidden stores batched in registers (hbuf[8], static idx), flushed at the
//    TOP of the next 8-step block -> stores retire under the MFMA phase and
//    the per-step __syncthreads vmcnt(0) drain costs ~nothing
//  - b_hh folded into MFMA acc init (math identical, validated by v3 run);
//    removes 3 serial LDS reads/step from the gate tail
//  - everything else byte-identical to v2 (incl. __syncthreads, NOT the v3
//    raw-barrier which regressed 1.8x)
// (Resubmit of R3: prior bench died with a container-infra error, no profile.)

typedef __attribute__((ext_vector_type(8))) _Float16 half8;   // 4 VGPRs
typedef __attribute__((ext_vector_type(4))) _Float16 half4;   // 2 VGPRs
typedef __attribute__((ext_vector_type(4))) float float4v;
typedef __attribute__((ext_vector_type(4))) float facc4;      // MFMA acc
typedef __attribute__((ext_vector_type(4))) unsigned short ushort4v;

#define GI_BYTES   (512 * 8 * 768 * 4)        // 12582912
#define HID_BYTES  (4096 * 256 * 2)           // 2097152
#define FLAG_OFF   (GI_BYTES + HID_BYTES)

__device__ __forceinline__ float b2f(unsigned short u) {
  union { unsigned int i; float f; } v; v.i = ((unsigned int)u) << 16; return v.f;
}
__device__ __forceinline__ unsigned short f2b(float f) {
  union { float f; unsigned int i; } v; v.f = f;
  unsigned int r = v.i + 0x7FFFu + ((v.i >> 16) & 1u);  // RNE
  return (unsigned short)(r >> 16);
}
template<bool BF> __device__ __forceinline__ float ldf(const void* p, int i) {
  if constexpr (BF) return b2f(((const unsigned short*)p)[i]);
  else              return ((const float*)p)[i];
}
template<bool BF> __device__ __forceinline__ float4v ld4(const void* p, int i) {
  float4v r;
  if constexpr (BF) {
    ushort4v u = *reinterpret_cast<const ushort4v*>((const unsigned short*)p + i);
#pragma unroll
    for (int j = 0; j < 4; ++j) r[j] = b2f(u[j]);
  } else {
    r = *reinterpret_cast<const float4v*>((const float*)p + i);
  }
  return r;
}

// ---- dtype detector: bf16 storage => low u16 of each u32 word has a small-
// value bf16 exponent pattern; f32 storage => those bits are uniform mantissa.
__global__ void k_detect(const unsigned int* __restrict__ emb_raw,
                         int* __restrict__ flag) {
  int tid = threadIdx.x;
  unsigned int u = emb_raw[tid];
  unsigned int lo = u & 0xFFFFu;
  unsigned int ex = (lo >> 7) & 0xFFu;        // bf16 exponent field
  int hit = ((ex >= 96u && ex <= 127u) || lo == 0u) ? 1 : 0;
  unsigned long long m = __ballot(hit);
  if (tid == 0) flag[0] = (__popcll(m) >= 40) ? 1 : 0;
}

// ---- kernel 1: gi[s][b][g] = emb[t[b,s]] . w_ih[g,:] + b_ih[g]  (f32 out) ----
template<bool BF>
__global__ __launch_bounds__(256, 4) void k_gi(
    const int* __restrict__ flag, const int* __restrict__ t,
    const void* __restrict__ emb, const void* __restrict__ w_ih,
    const void* __restrict__ b_ih, float* __restrict__ gi)
{
  if (*flag != (BF ? 1 : 0)) return;
  alignas(16) __shared__ float x_lds[4][128];
  const int n0 = blockIdx.x * 4;               // 4 tokens per block
  const int tid = threadIdx.x;
  for (int i = tid; i < 512; i += 256) {
    int tk = i >> 7, e = i & 127;
    int n = n0 + tk, s = n >> 3, b = n & 7;
    int tok = t[b * 512 + s];
    x_lds[tk][e] = ldf<BF>(emb, tok * 128 + e);
  }
  __syncthreads();
#pragma unroll
  for (int gg = 0; gg < 3; ++gg) {
    int g = gg * 256 + tid;
    float bias = ldf<BF>(b_ih, g);
    float a0 = bias, a1 = bias, a2 = bias, a3 = bias;
    for (int kb = 0; kb < 32; ++kb) {
      float4v w4 = ld4<BF>(w_ih, g * 128 + kb * 4);
#pragma unroll
      for (int j = 0; j < 4; ++j) {
        float w = w4[j]; int k = kb * 4 + j;
        a0 = fmaf(w, x_lds[0][k], a0);
        a1 = fmaf(w, x_lds[1][k], a1);
        a2 = fmaf(w, x_lds[2][k], a2);
        a3 = fmaf(w, x_lds[3][k], a3);
      }
    }
    gi[(n0 + 0) * 768 + g] = a0;
    gi[(n0 + 1) * 768 + g] = a1;
    gi[(n0 + 2) * 768 + g] = a2;
    gi[(n0 + 3) * 768 + g] = a3;
  }
}

// ---- kernel 2: serial GRU scan, one block per batch, 16 waves ----
template<bool BF>
__global__ __launch_bounds__(1024, 4) void k_scan(
    const int* __restrict__ flag, const void* __restrict__ w_hh,
    const void* __restrict__ b_hh, const void* __restrict__ h0,
    const float* __restrict__ gi, _Float16* __restrict__ hidden)
{
  if (*flag != (BF ? 1 : 0)) return;
  alignas(16) __shared__ _Float16 a_sh[2][256];   // h double-buffer, 1KB
  alignas(16) __shared__ float gi_sh[2][768];     // gi double-buffer, 6KB

  const int tid = threadIdx.x;
  const int b = blockIdx.x;                       // batch index
  const int wave = tid >> 6, lane = tid & 63;
  const int l15 = lane & 15, q = lane >> 4;
  const bool ard = (l15 == 0);                    // only row 0 of A is real
  const int qo = q * 8;                           // k sub-offset within kt
  const int j = (wave << 4) + l15;                // this lane's gate column

  // B fragments: tile tt = gate (r,z,n), cols j in [wave*16, wave*16+16).
  // B[k][col] = w_hh[row][k]; lane: col=l15 -> row = tt*256 + j,
  // k = kt*32 + q*8 + jj. Verified mapping (v2/v3 both passed).
  half8 bfr[3][8];
#pragma unroll
  for (int tt = 0; tt < 3; ++tt) {
    int nrow = tt * 256 + j;
#pragma unroll
    for (int kt = 0; kt < 8; ++kt) {
      int base = nrow * 256 + kt * 32 + qo;
      float4v x0 = ld4<BF>(w_hh, base), x1 = ld4<BF>(w_hh, base + 4);
      half8 h;
#pragma unroll
      for (int jj = 0; jj < 4; ++jj) { h[jj] = (_Float16)x0[jj]; h[4 + jj] = (_Float16)x1[jj]; }
      bfr[tt][kt] = h;
    }
  }

  // per-lane biases, folded into acc init (C col = l15 -> bias of column j
  // applies to every acc row; only row 0 is consumed). Step-invariant.
  const float bh_r = ldf<BF>(b_hh, j);
  const float bh_z = ldf<BF>(b_hh, 256 + j);
  const float bh_n = ldf<BF>(b_hh, 512 + j);

  if (tid < 256) a_sh[0][tid] = (_Float16)ldf<BF>(h0, tid);   // h(-1)
  if (tid < 768) gi_sh[0][tid] = gi[b * 768 + tid];           // gi(s=0)
  float hreg = (lane < 16) ? ldf<BF>(h0, j) : 0.f;            // f32 across steps

  half8 a0 = {}, a1 = {};   // inactive lanes (l15!=0) stay zero forever
  _Float16 hbuf[8];         // staged h values, static-indexed (rule #20)
  _Float16* hid = hidden + b * 512 * 256;
  __syncthreads();

  for (int so = 0; so < 512; so += 8) {
#pragma unroll
    for (int u = 0; u < 8; ++u) {
      const int s = so + u;
      const int p = u & 1;                         // compile-time parity

      // prefetch gi(s+1); coalesced, latency hides under the MFMA phase
      float gnext = 0.f;
      if (tid < 768 && s < 511) gnext = gi[(s + 1) * 6144 + b * 768 + tid];

      // flush previous 8-step block's h to global: stores retire under this
      // step's MFMAs, so the barrier's vmcnt(0) drain is nearly free
      if (u == 0 && so > 0 && lane < 16) {
#pragma unroll
        for (int v = 0; v < 8; ++v)
          hid[(so - 8 + v) * 256 + j] = hbuf[v];
      }

      const _Float16* ap = &a_sh[p][0];            // h(s-1)
      facc4 acc0 = {bh_r, bh_r, bh_r, bh_r};
      facc4 acc1 = {bh_z, bh_z, bh_z, bh_z};
      facc4 acc2 = {bh_n, bh_n, bh_n, bh_n};
      if (ard) a0 = *reinterpret_cast<const half8*>(ap + qo);
#pragma unroll
      for (int kt = 0; kt < 8; kt += 2) {
        if (ard) a1 = *reinterpret_cast<const half8*>(ap + (kt + 1) * 32 + qo);
        acc0 = __builtin_amdgcn_mfma_f32_16x16x32_f16(a0, bfr[0][kt], acc0, 0, 0, 0);
        acc1 = __builtin_amdgcn_mfma_f32_16x16x32_f16(a0, bfr[1][kt], acc1, 0, 0, 0);
        acc2 = __builtin_amdgcn_mfma_f32_16x16x32_f16(a0, bfr[2][kt], acc2, 0, 0, 0);
        if (ard && kt + 2 < 8) a0 = *reinterpret_cast<const half8*>(ap + (kt + 2) * 32 + qo);
        acc0 = __builtin_amdgcn_mfma_f32_16x16x32_f16(a1, bfr[0][kt + 1], acc0, 0, 0, 0);
        acc1 = __builtin_amdgcn_mfma_f32_16x16x32_f16(a1, bfr[1][kt + 1], acc1, 0, 0, 0);
        acc2 = __builtin_amdgcn_mfma_f32_16x16x32_f16(a1, bfr[2][kt + 1], acc2, 0, 0, 0);
      }

      // stage gi(s+1) into the other LDS buffer (nobody reads p^1 this step)
      if (tid < 768 && s < 511) gi_sh[p ^ 1][tid] = gnext;

      // gate math: C row 0 = (q==0, i==0) -> lanes 0..15 hold gh+bhh for
      // (batch b, col j) in acc0[0]/acc1[0]/acc2[0].
      if (lane < 16) {
        float gir = gi_sh[p][j], giz = gi_sh[p][256 + j], gin = gi_sh[p][512 + j];
        float r = 1.f / (1.f + __expf(-(gir + acc0[0])));
        float z = 1.f / (1.f + __expf(-(giz + acc1[0])));
        float xn = gin + r * acc2[0];
        float e2 = __expf(2.f * xn);
        float nn = 1.f - 2.f / (e2 + 1.f);           // tanh
        float hnew = (1.f - z) * nn + z * hreg;
        hreg = hnew;
        _Float16 hf = (_Float16)hnew;
        a_sh[p ^ 1][j] = hf;                         // h(s) -> next step's A
        hbuf[u] = hf;
      }
      __syncthreads();
    }
  }
  // epilogue: flush steps 504..511
  if (lane < 16) {
#pragma unroll
    for (int v = 0; v < 8; ++v)
      hid[(504 + v) * 256 + j] = hbuf[v];
  }
}

// ---- kernel 3: out[tok][v] = hidden[tok,:] . w_out[v,:] + b_out[v] ----
template<bool BF>
__global__ __launch_bounds__(256, 2) void k_out(
    const int* __restrict__ flag, const _Float16* __restrict__ hidden,
    const void* __restrict__ w_out, const void* __restrict__ b_out,
    void* __restrict__ out)
{
  if (*flag != (BF ? 1 : 0)) return;
  alignas(16) __shared__ _Float16 Asm[128 * 72];  // [m][k], +8 pad
  alignas(16) __shared__ _Float16 Bsm[128 * 72];  // [n][k], +8 pad
  // XCD-chunked swizzle (8000 % 8 == 0, bijective): measured neutral, kept.
  const int bid0 = blockIdx.x;
  const int bid = (bid0 & 7) * 1000 + (bid0 >> 3);
  const int m0 = (bid & 31) * 128;     // 32 m-blocks inner: w_out reuse
  const int n0 = (bid >> 5) * 128;     // 250 n-blocks
  const int tid = threadIdx.x;
  const int wave = tid >> 6, lane = tid & 63;
  const int l15 = lane & 15, q = lane >> 4;
  const int wm = (wave >> 1) * 64, wn = (wave & 1) * 64;

  facc4 acc[4][4] = {};
  float bo[4];
#pragma unroll
  for (int nt = 0; nt < 4; ++nt)
    bo[nt] = ldf<BF>(b_out, n0 + wn + nt * 16 + l15);

  for (int kk = 0; kk < 4; ++kk) {
    int k0 = kk * 64;
#pragma unroll
    for (int r = 0; r < 4; ++r) {
      int row = r * 32 + (tid >> 3);
      int ch = tid & 7;
      *reinterpret_cast<half8*>(&Asm[row * 72 + ch * 8]) =
          *reinterpret_cast<const half8*>(hidden + (m0 + row) * 256 + k0 + ch * 8);
      int wbase = (n0 + row) * 256 + k0 + ch * 8;
      float4v w0 = ld4<BF>(w_out, wbase), w1 = ld4<BF>(w_out, wbase + 4);
      half8 hB;
#pragma unroll
      for (int jj = 0; jj < 4; ++jj) { hB[jj] = (_Float16)w0[jj]; hB[4 + jj] = (_Float16)w1[jj]; }
      *reinterpret_cast<half8*>(&Bsm[row * 72 + ch * 8]) = hB;
    }
    __syncthreads();
#pragma unroll
    for (int kt = 0; kt < 2; ++kt) {
      int koff = kt * 32 + q * 8;
      half8 af[4], bf[4];
#pragma unroll
      for (int mt = 0; mt < 4; ++mt)
        af[mt] = *reinterpret_cast<const half8*>(&Asm[(wm + mt * 16 + l15) * 72 + koff]);
#pragma unroll
      for (int nt = 0; nt < 4; ++nt)
        bf[nt] = *reinterpret_cast<const half8*>(&Bsm[(wn + nt * 16 + l15) * 72 + koff]);
#pragma unroll
      for (int mt = 0; mt < 4; ++mt)
#pragma unroll
        for (int nt = 0; nt < 4; ++nt)
          acc[mt][nt] = __builtin_amdgcn_mfma_f32_16x16x32_f16(
              af[mt], bf[nt], acc[mt][nt], 0, 0, 0);
    }
    __syncthreads();
  }
#pragma unroll
  for (int mt = 0; mt < 4; ++mt) {
#pragma unroll
    for (int i = 0; i < 4; ++i) {
      int row = m0 + wm + mt * 16 + q * 4 + i;
#pragma unroll
      for (int nt = 0; nt < 4; ++nt) {
        int col = n0 + wn + nt * 16 + l15;
        float val = acc[mt][nt][i] + bo[nt];
        if constexpr (BF) ((unsigned short*)out)[row * 32000 + col] = f2b(val);
        else              ((float*)out)[row * 32000 + col] = val;
      }
    }
  }
}

extern "C" void kernel_launch(void* const* d_in, const int* in_sizes, int n_in,
                              void* d_out, int out_size, void* d_ws, size_t ws_size,
                              hipStream_t stream) {
  const int* t     = (const int*)d_in[0];
  const void* emb  = d_in[1];
  const void* h0   = d_in[2];
  const void* w_ih = d_in[3];
  const void* w_hh = d_in[4];
  const void* b_ih = d_in[5];
  const void* b_hh = d_in[6];
  const void* w_out = d_in[7];
  const void* b_out = d_in[8];

  float*     gi     = (float*)d_ws;
  _Float16*  hidden = (_Float16*)((char*)d_ws + GI_BYTES);
  int*       flag   = (int*)((char*)d_ws + FLAG_OFF);

  k_detect<<<1, 64, 0, stream>>>((const unsigned int*)emb, flag);

  k_gi<false><<<1024, 256, 0, stream>>>(flag, t, emb, w_ih, b_ih, gi);
  k_gi<true> <<<1024, 256, 0, stream>>>(flag, t, emb, w_ih, b_ih, gi);

  k_scan<false><<<8, 1024, 0, stream>>>(flag, w_hh, b_hh, h0, gi, hidden);
  k_scan<true> <<<8, 1024, 0, stream>>>(flag, w_hh, b_hh, h0, gi, hidden);

  k_out<false><<<8000, 256, 0, stream>>>(flag, hidden, w_out, b_out, d_out);
  k_out<true> <<<8000, 256, 0, stream>>>(flag, hidden, w_out, b_out, d_out);
}